// Round 6
// baseline (173.315 us; speedup 1.0000x reference)
//
#include <hip/hip_runtime.h>

// AP (average precision @ IoU 0.5/0.75) for B=256, N=4000, G=50.
// Strategy: greedy TP matching -> <=50 TPs per (batch,thr); exact stable
// descending-sort ranks of TPs via 4096-bucket counting sort of the 1.024M
// confidences; AP from TP ranks only.
//
// R1: pos 390us latency loop -> LDS. R2-R4: tp stuck ~145us on 1M global
//     hist atomics -> zero-global-atomic design. R5 crash (LDS>64KB).
// R6: 423us. R7: rank one-wave-per-slot; 260. R8: pos1/pos2 split; 204.
// R9: g-outer neutral. R10: bit-exact divide elimination; 191.
// R11: s1/pos2/u64-key bundle neutral; 192.
// R12/R13: cand->global eviction REGRESSED (222us): at grid==CU-count,
//     LDS < 64KB is FREE; eviction added 12.8MB of 8B stores.
// R14: NBKT 1024->2048; 187. R15: pos1+ap -> LDS counting-sort sortap; 169.8.
// R16: coop-kernel full fusion REGRESSED (308): grid.sync spin + rank lost
//     latency hiding. One 268MB ws-poison fill/iter ~45us is fixed cost.
// R17: s1 tiled + s2 folded into scatter: NEUTRAL (168.1).
// R18: exact-f32 IoU predicate (no f64 in tp) + NBKT 4096: 163.8.
// R19: H-S scans -> wave-shuffle scans: 159.0. COUNTER FIND: sortap is
//     ~46us @ 0.2% VALUBusy -- 2-block mega-LDS kernels pay a ~45-50us
//     latency wall (old R14 ap did too); full-GPU pos1 doing 328M compares
//     measured 8-9us. LESSON: phase shape >> op count at this scale.
// R20: kill the 2-block wall: sortap -> pos1 (R14-verbatim all-pairs
//     partial counts, 416 blocks) + sumpr (full-GPU partial-sum + pr
//     divide + bijective scatter of (pr, rank) into sorted order) +
//     apfin (2 blocks, MINIMAL: 8KB LDS, shuffle suffix-max, verbatim
//     double-tree sum). Same arithmetic, same order, absmax 0 expected.

#define B_ 256
#define N_ 4000
#define G_ 50
#define M_ (B_ * N_)        // 1,024,000 proposals total
#define NL_ (B_ * G_)       // 12,800 labels total (= n_labels)
#define NBKT 4096           // score-counting-sort buckets
#define KP 16               // pos1 k-tile count
#define TILE (NL_ / KP)     // 800

typedef unsigned long long u64;

__device__ __forceinline__ unsigned bucket_of(float c) {
    unsigned b = (unsigned)(c * 4096.0f);
    return b > (NBKT - 1) ? (NBKT - 1) : b;
}

// ---- Phase 1: IoU cand masks + greedy (both thr) + LDS histogram. ---------
// One 1024-thread block per batch; grid==256 -> 1 block/CU, LDS is free.
__global__ __launch_bounds__(1024) void tp_kernel(
    const float* __restrict__ seg,    // [B,N,2]
    const float* __restrict__ gts,    // [B,G,2]
    const float* __restrict__ conf,   // [B,N]
    int* __restrict__ tpIdx,          // [2][NL_], slots [b*50, b*50+cnt)
    int* __restrict__ cnt,            // [2][B_]
    unsigned short* __restrict__ pbh) // [B_][NBKT] per-batch histogram
{
    const int tid  = threadIdx.x;
    const int lane = tid & 63;
    const int wv   = tid >> 6;            // wave id 0..15
    const int b    = blockIdx.x;

    __shared__ float2 gtl[G_];            // 400 B
    __shared__ u64 cand[2][G_][64];       // 51.2 KiB
    __shared__ unsigned hls[NBKT / 2];    // 8 KiB (u16-packed bin pairs)
    __shared__ int lcnt[2];               // total 59.8 KiB < 64 KiB

    #pragma unroll
    for (int k = 0; k < NBKT / 2048; ++k) hls[k * 1024 + tid] = 0u;
    if (tid < G_) gtl[tid] = ((const float2*)gts)[b * G_ + tid];
    if (tid < 2) lcnt[tid] = 0;
    __syncthreads();

    // LDS-private histogram; packed u16 pairs (per-batch bin count <= 4000,
    // so no carry across the 16-bit fields).
    const float* cb = conf + (size_t)b * N_;
    #pragma unroll
    for (int s = 0; s < 4; ++s) {
        int n = s * 1024 + tid;
        if (n < N_) {
            unsigned bin = bucket_of(cb[n]);
            atomicAdd(&hls[bin >> 1], 1u << ((bin & 1) * 16));
        }
    }

    // Phase A (g outer, slots inner): props in registers, gt read once per g.
    const float2* sb = (const float2*)(seg + (size_t)b * (N_ * 2));
    float pmin[4], pmax[4], plen[4];
    #pragma unroll
    for (int s = 0; s < 4; ++s) {
        int n = s * 1024 + tid;
        if (n < N_) { float2 v = sb[n]; pmin[s] = v.x; pmax[s] = v.y; }
        else { pmin[s] = 1e9f; pmax[s] = 1e9f; }   // sentinel -> iou 0
        plen[s] = pmax[s] - pmin[s];               // == ref's (amax - amin)
    }
    for (int g = 0; g < G_; ++g) {
        float2 gt = gtl[g];                        // one LDS broadcast per g
        float glen = gt.y - gt.x;
        u64 m0[4], m1[4];
        #pragma unroll
        for (int s = 0; s < 4; ++s) {
            float inter = fmaxf(fminf(pmax[s], gt.y) - fmaxf(pmin[s], gt.x), 0.0f);
            float uni = plen[s] + glen - inter;    // f32, same op order as ref
            // Exact predicate: fl32(inter/uni) > thr  <=>  inter > (thr+2^-25)*uni.
            // d = inter - 0.5*uni is Sterbenz-exact for inter >= 0.25*uni (covers
            // the decision boundary; robustly negative below). e25 = 2^-25*uni is
            // always exact. (d - 0.25*uni) exact for inter in [0.625u, u].
            float e25 = uni * 0x1p-25f;
            float d   = inter - 0.5f * uni;
            m0[s] = __ballot(d > e25);                   // == fl(i/u) > 0.5f
            m1[s] = __ballot((d - 0.25f * uni) > e25);   // == fl(i/u) > 0.75f
        }
        if (lane == 0) {                           // one branch, 8 LDS stores
            #pragma unroll
            for (int s = 0; s < 4; ++s) {
                cand[0][g][s * 16 + wv] = m0[s];
                cand[1][g][s * 16 + wv] = m1[s];
            }
        }
    }
    __syncthreads();   // cand complete + hist complete

    // write per-batch histogram row: packed u32 layout == u16[bin] layout
    {
        unsigned* prow = (unsigned*)(pbh + (size_t)b * NBKT);
        #pragma unroll
        for (int k = 0; k < NBKT / 2048; ++k)
            prow[k * 1024 + tid] = hls[k * 1024 + tid];
    }

    // Phase B: wave 0 -> thr 0.5, wave 1 -> thr 0.75. Greedy via ballot+ffs.
    if (wv < 2) {
        const int thr_i = wv;
        u64 used = 0ull;                     // proposals [lane*64, lane*64+64)
        for (int g = 0; g < G_; ++g) {
            u64 c = cand[thr_i][g][lane] & ~used;
            u64 ball = __ballot(c != 0ull);
            if (ball) {
                int fl = __ffsll(ball) - 1;  // lowest lane = lowest proposal range
                if (lane == fl) used |= (c & (0ull - c));   // lowest set bit
            }
        }
        int cpop = __popcll(used);
        if (cpop) {
            int j = atomicAdd(&lcnt[thr_i], cpop);   // LDS atomic, block-local
            u64 u = used;
            while (u) {
                int bit = __ffsll(u) - 1;
                u &= u - 1;
                tpIdx[thr_i * NL_ + b * G_ + j++] = b * N_ + lane * 64 + bit;
            }
        }
    }
    __syncthreads();
    if (tid < 2) cnt[tid * B_ + b] = lcnt[tid];
}

// ---- S1: tiled column scan. 128 blocks x 32 bins; tile [256 batches][32] --
__global__ __launch_bounds__(256) void s1_kernel(
    unsigned short* __restrict__ pbh,        // [B_][NBKT] -> becomes prefix
    unsigned* __restrict__ total)            // [NBKT]
{
    __shared__ unsigned short tile[256][32]; // 16 KiB
    __shared__ unsigned segsum[8][32];       // 1 KiB
    const int j = blockIdx.x;                // bins [j*32, j*32+32)
    const int t = threadIdx.x;               // batch row (for load/store)
    uint4* dst = (uint4*)&tile[t][0];
    const uint4* src = (const uint4*)(pbh + (size_t)t * NBKT + j * 32);
    #pragma unroll
    for (int k = 0; k < 4; ++k) dst[k] = src[k];      // 64 B, one line
    __syncthreads();

    const int col = t & 31, seg = t >> 5;    // 8 segments of 32 batches
    unsigned run = 0;
    #pragma unroll
    for (int i = 0; i < 32; ++i) run += tile[seg * 32 + i][col];
    segsum[seg][col] = run;
    __syncthreads();
    unsigned off0 = 0;
    #pragma unroll
    for (int s = 0; s < 8; ++s) off0 += (s < seg) ? segsum[s][col] : 0u;
    if (seg == 7) total[j * 32 + col] = off0 + segsum[7][col];
    unsigned run2 = off0;                    // exclusive prefix write-back
    #pragma unroll
    for (int i = 0; i < 32; ++i) {
        unsigned v = tile[seg * 32 + i][col];
        tile[seg * 32 + i][col] = (unsigned short)run2;
        run2 += v;
    }
    __syncthreads();
    uint4* back = (uint4*)(pbh + (size_t)t * NBKT + j * 32);
    #pragma unroll
    for (int k = 0; k < 4; ++k) back[k] = dst[k];     // coalesced write-back
}

// ---- Scatter (+ fused s2: wave-shuffle scan of 4096 totals) --------------
// key = bits(conf)<<32 | ~idx : u64 ordering == (conf desc, idx asc) exactly.
__global__ __launch_bounds__(1024) void scatter_kernel(
    const float* __restrict__ conf,
    const unsigned short* __restrict__ pbh,  // now the exclusive prefix
    const unsigned* __restrict__ total,
    unsigned* __restrict__ binStartG,        // published by block 0 for rank
    u64* __restrict__ sKey)
{
    __shared__ unsigned baseB[NBKT];   // 16 KiB
    __shared__ unsigned lofs[NBKT];    // 16 KiB
    __shared__ unsigned wtot[16];
    const int tid = threadIdx.x;
    const int lane = tid & 63;
    const int wv = tid >> 6;
    const int b = blockIdx.x;

    // s2 inlined: shuffle-based exclusive scan of 4096 totals (4/thread)
    uint4 v4 = ((const uint4*)total)[tid];
    unsigned own = v4.x + v4.y + v4.z + v4.w;
    unsigned inc = own;
    #pragma unroll
    for (int off = 1; off < 64; off <<= 1) {
        unsigned o = __shfl_up(inc, off, 64);
        if (lane >= off) inc += o;
    }
    if (lane == 63) wtot[wv] = inc;
    __syncthreads();
    if (wv == 0) {                          // exclusive scan of 16 wave totals
        unsigned w = (lane < 16) ? wtot[lane] : 0u;
        unsigned wi = w;
        #pragma unroll
        for (int off = 1; off < 16; off <<= 1) {
            unsigned o = __shfl_up(wi, off, 64);
            if (lane >= off) wi += o;
        }
        if (lane < 16) wtot[lane] = wi - w;
    }
    __syncthreads();
    unsigned start = (inc - own) + wtot[wv];     // exclusive global prefix
    baseB[4 * tid]     = start;                  // exclusive bin starts
    baseB[4 * tid + 1] = start + v4.x;
    baseB[4 * tid + 2] = start + v4.x + v4.y;
    baseB[4 * tid + 3] = start + v4.x + v4.y + v4.z;
    __syncthreads();
    #pragma unroll
    for (int k = 0; k < 4; ++k) {
        int bin = k * 1024 + tid;
        unsigned bs = baseB[bin];
        if (b == 0) binStartG[bin] = bs;    // publish for rank_kernel
        baseB[bin] = bs + pbh[(size_t)b * NBKT + bin];
        lofs[bin] = 0u;
    }
    __syncthreads();

    const float* cb = conf + (size_t)b * N_;
    #pragma unroll
    for (int s4 = 0; s4 < 4; ++s4) {
        int n = s4 * 1024 + tid;
        if (n < N_) {
            float c = cb[n];
            unsigned bin = bucket_of(c);
            unsigned lo = atomicAdd(&lofs[bin], 1u);   // LDS atomic
            unsigned idx = (unsigned)(b * N_ + n);
            sKey[baseB[bin] + lo] = ((u64)__float_as_uint(c) << 32) | (u64)(0xFFFFFFFFu - idx);
        }
    }
}

// ---- Rank: one WAVE per TP slot; lanes stride the ~250-elem bucket --------
__global__ __launch_bounds__(256) void rank_kernel(
    const float* __restrict__ conf,
    const int* __restrict__ tpIdx,
    const int* __restrict__ cnt,
    const unsigned* __restrict__ total,
    const unsigned* __restrict__ binStart,
    const u64* __restrict__ sKey,
    int* __restrict__ tpRank)
{
    const int lane = threadIdx.x & 63;
    const int w = (blockIdx.x << 2) | (threadIdx.x >> 6);   // global wave id
    if (w >= 2 * NL_) return;
    const int thr_i = w / NL_;
    const int t = w - thr_i * NL_;
    const int batch = t / G_;
    const int j = t - batch * G_;

    if (j < cnt[thr_i * B_ + batch]) {
        int e = tpIdx[thr_i * NL_ + t];
        float c = conf[e];
        u64 keyE = ((u64)__float_as_uint(c) << 32) | (u64)(0xFFFFFFFFu - (unsigned)e);
        unsigned bin = bucket_of(c);
        unsigned lo = binStart[bin], n = total[bin];
        int r = M_ - (int)lo - (int)n;   // strictly-better buckets
        for (unsigned base = 0; base < n; base += 64) {
            unsigned k = base + lane;
            bool pred = (k < n) && (sKey[lo + k] > keyE);
            r += (int)__popcll(__ballot(pred));   // wave-uniform partial sum
        }
        if (lane == 0) tpRank[thr_i * NL_ + t] = r;
    } else {
        if (lane == 0) tpRank[thr_i * NL_ + t] = M_ + t;   // distinct sentinel
    }
}

// ---- Pos1 (R14-verbatim): partial counts, 4 t's per lane, K=16 u-tiles ----
// pos(t) = sum over k of pcount[k][t] = #{t' : rank_{t'} < rank_t}.
// Ranks are distinct (incl. sentinels M_+t) -> positions are a bijection.
__global__ __launch_bounds__(256) void pos1_kernel(
    const int* __restrict__ tpRank,
    int* __restrict__ pcount)          // [2][KP][NL_]
{
    __shared__ alignas(16) int tile[TILE];
    const int k = blockIdx.y, thr_i = blockIdx.z;
    const int* base = tpRank + thr_i * NL_;
    for (int i = threadIdx.x; i < TILE; i += 256)
        tile[i] = base[k * TILE + i];
    __syncthreads();

    const int t0 = blockIdx.x * 1024 + threadIdx.x;
    int r[4], c[4] = {0, 0, 0, 0};
    #pragma unroll
    for (int j = 0; j < 4; ++j) {
        int t = t0 + j * 256;
        r[j] = (t < NL_) ? base[t] : -1;   // ranks >= 0, so c stays 0
    }
    const int4* l4 = (const int4*)tile;
    #pragma unroll 4
    for (int i = 0; i < TILE / 4; ++i) {   // wave-uniform -> LDS broadcast
        int4 v = l4[i];
        #pragma unroll
        for (int j = 0; j < 4; ++j)
            c[j] += (v.x < r[j]) + (v.y < r[j]) + (v.z < r[j]) + (v.w < r[j]);
    }
    #pragma unroll
    for (int j = 0; j < 4; ++j) {
        int t = t0 + j * 256;
        if (t < NL_) pcount[(thr_i * KP + k) * NL_ + t] = c[j];
    }
}

// ---- SumPr: full-GPU partial sum -> position; pr divide; bijective scatter.
// prA[thr][pos] = (pos+1)/(rank+1) for valid TPs, -1 for sentinels.
// rkA[thr][pos] = rank. Every slot written exactly once (bijection).
__global__ __launch_bounds__(256) void sumpr_kernel(
    const int* __restrict__ tpRank,
    const int* __restrict__ pcount,
    float* __restrict__ prA,
    int* __restrict__ rkA)
{
    const int thr_i = blockIdx.y;
    const int t = blockIdx.x * 256 + threadIdx.x;   // NL_ = 50*256 exact
    int p = 0;
    #pragma unroll
    for (int k = 0; k < KP; ++k)
        p += pcount[(thr_i * KP + k) * NL_ + t];    // coalesced
    int r = tpRank[thr_i * NL_ + t];
    float pr = (r < M_) ? (float)(p + 1) / (float)(r + 1) : -1.0f;
    prA[thr_i * NL_ + p] = pr;
    rkA[thr_i * NL_ + p] = r;
}

// ---- ApFin: 2 blocks, MINIMAL content (8KB LDS). Loads sorted (pr, rank),
// shuffle suffix-max, verbatim double-tree sum (preserves absmax-0 order).
__global__ __launch_bounds__(1024) void apfin_kernel(
    const float* __restrict__ prA,
    const int* __restrict__ rkA,
    float* __restrict__ out)
{
    const int C = 13;   // 1024*13 = 13312 >= NL_
    __shared__ double red[1024];       // 8 KiB
    __shared__ float wmaxs[16];
    const int thr_i = blockIdx.x;
    const int t = threadIdx.x;
    const int lane = t & 63;
    const int wv = t >> 6;

    float pr[C]; int rk[C];
    #pragma unroll
    for (int k = 0; k < C; ++k) {
        int i = t * C + k;
        if (i < NL_) { pr[k] = prA[thr_i * NL_ + i]; rk[k] = rkA[thr_i * NL_ + i]; }
        else { pr[k] = -1.0f; rk[k] = 0x7FFFFFFF; }
    }
    float suf[C];
    float run = -1.0f;
    #pragma unroll
    for (int k = C - 1; k >= 0; --k) { run = fmaxf(run, pr[k]); suf[k] = run; }

    // shuffle-based suffix max: follow(t) = max over threads > t of run
    float m = run;
    #pragma unroll
    for (int off = 1; off < 64; off <<= 1) {
        float o = __shfl_down(m, off, 64);
        if (lane + off < 64) m = fmaxf(m, o);
    }
    float f_in = __shfl_down(m, 1, 64);    // suffix from lane+1 in-wave
    if (lane == 63) f_in = -1.0f;
    if (lane == 0) wmaxs[wv] = m;          // wave max
    __syncthreads();
    if (wv == 0) {
        float wm = (lane < 16) ? wmaxs[lane] : -1.0f;
        float mi = wm;
        #pragma unroll
        for (int off = 1; off < 16; off <<= 1) {
            float o = __shfl_down(mi, off, 64);
            if (lane + off < 64) mi = fmaxf(mi, o);
        }
        float fw = __shfl_down(mi, 1, 64); // suffix from wave lane+1
        if (lane >= 15) fw = -1.0f;
        if (lane < 16) wmaxs[lane] = fw;
    }
    __syncthreads();
    float follow = fmaxf(f_in, wmaxs[wv]);

    double acc = 0.0;
    #pragma unroll
    for (int k = 0; k < C; ++k) {
        int i = t * C + k;
        if (rk[k] >= 1 && rk[k] < M_) {   // global rank 0 excluded by ref curve
            float smax = fmaxf(suf[k], follow);
            float rhi = (float)(i + 1) / 12800.0f;
            float rlo = (float)i / 12800.0f;
            acc += (double)((rhi - rlo) * smax);
        }
    }
    red[t] = acc;
    __syncthreads();
    for (int off = 512; off >= 1; off >>= 1) {
        if (t < off) red[t] += red[t + off];
        __syncthreads();
    }
    if (t == 0) out[thr_i] = (float)red[0];
}

extern "C" void kernel_launch(void* const* d_in, const int* in_sizes, int n_in,
                              void* d_out, int out_size, void* d_ws, size_t ws_size,
                              hipStream_t stream) {
    const float* scores = (const float*)d_in[0];   // [B,N]
    const float* seg    = (const float*)d_in[1];   // [B,N,2]
    const float* gts    = (const float*)d_in[2];   // [B,G,2]
    float* out = (float*)d_out;

    char* p = (char*)d_ws;
    int*            cnt        = (int*)p;             p += 4096;                  // 2KB used
    int*            tpIdx      = (int*)p;             p += 2 * NL_ * 4;           // 100 KB
    int*            tpRank     = (int*)p;             p += 2 * NL_ * 4;           // 100 KB
    unsigned*       total      = (unsigned*)p;        p += NBKT * 4;              // 16 KB
    unsigned*       binStart   = (unsigned*)p;        p += NBKT * 4;              // 16 KB
    unsigned short* pbh        = (unsigned short*)p;  p += (size_t)B_ * NBKT * 2; // 2 MB
    u64*            sKey       = (u64*)p;             p += (size_t)M_ * 8;        // 8 MB
    float*          prA        = (float*)p;           p += 2 * NL_ * 4;           // 100 KB
    int*            rkA        = (int*)p;             p += 2 * NL_ * 4;           // 100 KB
    int*            pcount     = (int*)sKey;    // aliases sKey (dead after rank)
    (void)ws_size; (void)in_sizes; (void)n_in; (void)out_size;

    // No memset: every workspace word read downstream is written upstream
    // (prA/rkA fully written by sumpr's bijective scatter).
    tp_kernel<<<B_, 1024, 0, stream>>>(seg, gts, scores, tpIdx, cnt, pbh);
    s1_kernel<<<NBKT / 32, 256, 0, stream>>>(pbh, total);
    scatter_kernel<<<B_, 1024, 0, stream>>>(scores, pbh, total, binStart, sKey);
    rank_kernel<<<(2 * NL_ + 3) / 4, 256, 0, stream>>>(scores, tpIdx, cnt,
                                                       total, binStart, sKey, tpRank);
    pos1_kernel<<<dim3(13, KP, 2), 256, 0, stream>>>(tpRank, pcount);
    sumpr_kernel<<<dim3(50, 2), 256, 0, stream>>>(tpRank, pcount, prA, rkA);
    apfin_kernel<<<2, 1024, 0, stream>>>(prA, rkA, out);
}

// Round 7
// 156.262 us; speedup vs baseline: 1.1091x; 1.1091x over previous
//
#include <hip/hip_runtime.h>

// AP (average precision @ IoU 0.5/0.75) for B=256, N=4000, G=50.
// Strategy: greedy TP matching -> <=50 TPs per (batch,thr); exact stable
// descending-sort ranks of TPs via 4096-bucket counting sort of the 1.024M
// confidences; AP from TP ranks only.
//
// R1: pos 390us latency loop -> LDS. R2-R4: tp stuck ~145us on 1M global
//     hist atomics -> zero-global-atomic design. R5 crash (LDS>64KB).
// R6: 423us. R7: rank one-wave-per-slot; 260. R8: pos1/pos2 split; 204.
// R9: g-outer neutral. R10: bit-exact divide elimination; 191.
// R11: s1/pos2/u64-key bundle neutral; 192.
// R12/R13: cand->global eviction REGRESSED (222us): at grid==CU-count,
//     LDS < 64KB is FREE; eviction added 12.8MB of 8B stores.
// R14: NBKT 1024->2048; 187. R15: pos1+ap -> LDS counting-sort sortap; 169.8.
// R16: coop-kernel full fusion REGRESSED (308): grid.sync spin + rank lost
//     latency hiding. One 268MB ws-poison fill/iter ~45us is fixed cost
//     (x2 = ~90us/iter fixed harness overhead).
// R17: s1 tiled + s2 folded into scatter: NEUTRAL (168.1).
// R18: exact-f32 IoU predicate (no f64 in tp) + NBKT 4096: 163.8.
// R19: H-S scans -> wave-shuffle scans: 159.0.
// R20: sortap -> pos1+sumpr+apfin REGRESSED (173.3). The R19 "sortap=46us"
//     row was _ord 4 = a COLD WARM-UP dispatch, not steady state; steady
//     sortap ~8us (2-block kernel floor; content ~free). The split paid
//     pos1(9)+apfin(8, same floor)+2 boundaries for it. LESSON: top-5
//     rocprof rows mix warm-up dispatches; one cold dispatch masquerades
//     as steady-state. Read per-kernel medians/ords before believing it.
// R21: revert to R19 (159.0) + one bit-exact micro-win: rank scans 2
//     keys/lane via 16B ulonglong2 loads (even-aligned base, range-masked;
//     identical predicate) -> bucket scan 4->2 round trips per wave.

#define B_ 256
#define N_ 4000
#define G_ 50
#define M_ (B_ * N_)        // 1,024,000 proposals total
#define NL_ (B_ * G_)       // 12,800 labels total (= n_labels)
#define NBKT 4096           // score-counting-sort buckets
#define SBKT 2048           // sortap's internal rank-radix buckets

typedef unsigned long long u64;

__device__ __forceinline__ unsigned bucket_of(float c) {
    unsigned b = (unsigned)(c * 4096.0f);
    return b > (NBKT - 1) ? (NBKT - 1) : b;
}

// ---- Phase 1: IoU cand masks + greedy (both thr) + LDS histogram. ---------
// One 1024-thread block per batch; grid==256 -> 1 block/CU, LDS is free.
__global__ __launch_bounds__(1024) void tp_kernel(
    const float* __restrict__ seg,    // [B,N,2]
    const float* __restrict__ gts,    // [B,G,2]
    const float* __restrict__ conf,   // [B,N]
    int* __restrict__ tpIdx,          // [2][NL_], slots [b*50, b*50+cnt)
    int* __restrict__ cnt,            // [2][B_]
    unsigned short* __restrict__ pbh) // [B_][NBKT] per-batch histogram
{
    const int tid  = threadIdx.x;
    const int lane = tid & 63;
    const int wv   = tid >> 6;            // wave id 0..15
    const int b    = blockIdx.x;

    __shared__ float2 gtl[G_];            // 400 B
    __shared__ u64 cand[2][G_][64];       // 51.2 KiB
    __shared__ unsigned hls[NBKT / 2];    // 8 KiB (u16-packed bin pairs)
    __shared__ int lcnt[2];               // total 59.8 KiB < 64 KiB

    #pragma unroll
    for (int k = 0; k < NBKT / 2048; ++k) hls[k * 1024 + tid] = 0u;
    if (tid < G_) gtl[tid] = ((const float2*)gts)[b * G_ + tid];
    if (tid < 2) lcnt[tid] = 0;
    __syncthreads();

    // LDS-private histogram; packed u16 pairs (per-batch bin count <= 4000,
    // so no carry across the 16-bit fields).
    const float* cb = conf + (size_t)b * N_;
    #pragma unroll
    for (int s = 0; s < 4; ++s) {
        int n = s * 1024 + tid;
        if (n < N_) {
            unsigned bin = bucket_of(cb[n]);
            atomicAdd(&hls[bin >> 1], 1u << ((bin & 1) * 16));
        }
    }

    // Phase A (g outer, slots inner): props in registers, gt read once per g.
    const float2* sb = (const float2*)(seg + (size_t)b * (N_ * 2));
    float pmin[4], pmax[4], plen[4];
    #pragma unroll
    for (int s = 0; s < 4; ++s) {
        int n = s * 1024 + tid;
        if (n < N_) { float2 v = sb[n]; pmin[s] = v.x; pmax[s] = v.y; }
        else { pmin[s] = 1e9f; pmax[s] = 1e9f; }   // sentinel -> iou 0
        plen[s] = pmax[s] - pmin[s];               // == ref's (amax - amin)
    }
    for (int g = 0; g < G_; ++g) {
        float2 gt = gtl[g];                        // one LDS broadcast per g
        float glen = gt.y - gt.x;
        u64 m0[4], m1[4];
        #pragma unroll
        for (int s = 0; s < 4; ++s) {
            float inter = fmaxf(fminf(pmax[s], gt.y) - fmaxf(pmin[s], gt.x), 0.0f);
            float uni = plen[s] + glen - inter;    // f32, same op order as ref
            // Exact predicate: fl32(inter/uni) > thr  <=>  inter > (thr+2^-25)*uni.
            // d = inter - 0.5*uni is Sterbenz-exact for inter >= 0.25*uni (covers
            // the decision boundary; robustly negative below). e25 = 2^-25*uni is
            // always exact. (d - 0.25*uni) exact for inter in [0.625u, u].
            float e25 = uni * 0x1p-25f;
            float d   = inter - 0.5f * uni;
            m0[s] = __ballot(d > e25);                   // == fl(i/u) > 0.5f
            m1[s] = __ballot((d - 0.25f * uni) > e25);   // == fl(i/u) > 0.75f
        }
        if (lane == 0) {                           // one branch, 8 LDS stores
            #pragma unroll
            for (int s = 0; s < 4; ++s) {
                cand[0][g][s * 16 + wv] = m0[s];
                cand[1][g][s * 16 + wv] = m1[s];
            }
        }
    }
    __syncthreads();   // cand complete + hist complete

    // write per-batch histogram row: packed u32 layout == u16[bin] layout
    {
        unsigned* prow = (unsigned*)(pbh + (size_t)b * NBKT);
        #pragma unroll
        for (int k = 0; k < NBKT / 2048; ++k)
            prow[k * 1024 + tid] = hls[k * 1024 + tid];
    }

    // Phase B: wave 0 -> thr 0.5, wave 1 -> thr 0.75. Greedy via ballot+ffs.
    if (wv < 2) {
        const int thr_i = wv;
        u64 used = 0ull;                     // proposals [lane*64, lane*64+64)
        for (int g = 0; g < G_; ++g) {
            u64 c = cand[thr_i][g][lane] & ~used;
            u64 ball = __ballot(c != 0ull);
            if (ball) {
                int fl = __ffsll(ball) - 1;  // lowest lane = lowest proposal range
                if (lane == fl) used |= (c & (0ull - c));   // lowest set bit
            }
        }
        int cpop = __popcll(used);
        if (cpop) {
            int j = atomicAdd(&lcnt[thr_i], cpop);   // LDS atomic, block-local
            u64 u = used;
            while (u) {
                int bit = __ffsll(u) - 1;
                u &= u - 1;
                tpIdx[thr_i * NL_ + b * G_ + j++] = b * N_ + lane * 64 + bit;
            }
        }
    }
    __syncthreads();
    if (tid < 2) cnt[tid * B_ + b] = lcnt[tid];
}

// ---- S1: tiled column scan. 128 blocks x 32 bins; tile [256 batches][32] --
__global__ __launch_bounds__(256) void s1_kernel(
    unsigned short* __restrict__ pbh,        // [B_][NBKT] -> becomes prefix
    unsigned* __restrict__ total)            // [NBKT]
{
    __shared__ unsigned short tile[256][32]; // 16 KiB
    __shared__ unsigned segsum[8][32];       // 1 KiB
    const int j = blockIdx.x;                // bins [j*32, j*32+32)
    const int t = threadIdx.x;               // batch row (for load/store)
    uint4* dst = (uint4*)&tile[t][0];
    const uint4* src = (const uint4*)(pbh + (size_t)t * NBKT + j * 32);
    #pragma unroll
    for (int k = 0; k < 4; ++k) dst[k] = src[k];      // 64 B, one line
    __syncthreads();

    const int col = t & 31, seg = t >> 5;    // 8 segments of 32 batches
    unsigned run = 0;
    #pragma unroll
    for (int i = 0; i < 32; ++i) run += tile[seg * 32 + i][col];
    segsum[seg][col] = run;
    __syncthreads();
    unsigned off0 = 0;
    #pragma unroll
    for (int s = 0; s < 8; ++s) off0 += (s < seg) ? segsum[s][col] : 0u;
    if (seg == 7) total[j * 32 + col] = off0 + segsum[7][col];
    unsigned run2 = off0;                    // exclusive prefix write-back
    #pragma unroll
    for (int i = 0; i < 32; ++i) {
        unsigned v = tile[seg * 32 + i][col];
        tile[seg * 32 + i][col] = (unsigned short)run2;
        run2 += v;
    }
    __syncthreads();
    uint4* back = (uint4*)(pbh + (size_t)t * NBKT + j * 32);
    #pragma unroll
    for (int k = 0; k < 4; ++k) back[k] = dst[k];     // coalesced write-back
}

// ---- Scatter (+ fused s2: wave-shuffle scan of 4096 totals) --------------
// key = bits(conf)<<32 | ~idx : u64 ordering == (conf desc, idx asc) exactly.
__global__ __launch_bounds__(1024) void scatter_kernel(
    const float* __restrict__ conf,
    const unsigned short* __restrict__ pbh,  // now the exclusive prefix
    const unsigned* __restrict__ total,
    unsigned* __restrict__ binStartG,        // published by block 0 for rank
    u64* __restrict__ sKey)
{
    __shared__ unsigned baseB[NBKT];   // 16 KiB
    __shared__ unsigned lofs[NBKT];    // 16 KiB
    __shared__ unsigned wtot[16];
    const int tid = threadIdx.x;
    const int lane = tid & 63;
    const int wv = tid >> 6;
    const int b = blockIdx.x;

    // s2 inlined: shuffle-based exclusive scan of 4096 totals (4/thread)
    uint4 v4 = ((const uint4*)total)[tid];
    unsigned own = v4.x + v4.y + v4.z + v4.w;
    unsigned inc = own;
    #pragma unroll
    for (int off = 1; off < 64; off <<= 1) {
        unsigned o = __shfl_up(inc, off, 64);
        if (lane >= off) inc += o;
    }
    if (lane == 63) wtot[wv] = inc;
    __syncthreads();
    if (wv == 0) {                          // exclusive scan of 16 wave totals
        unsigned w = (lane < 16) ? wtot[lane] : 0u;
        unsigned wi = w;
        #pragma unroll
        for (int off = 1; off < 16; off <<= 1) {
            unsigned o = __shfl_up(wi, off, 64);
            if (lane >= off) wi += o;
        }
        if (lane < 16) wtot[lane] = wi - w;
    }
    __syncthreads();
    unsigned start = (inc - own) + wtot[wv];     // exclusive global prefix
    baseB[4 * tid]     = start;                  // exclusive bin starts
    baseB[4 * tid + 1] = start + v4.x;
    baseB[4 * tid + 2] = start + v4.x + v4.y;
    baseB[4 * tid + 3] = start + v4.x + v4.y + v4.z;
    __syncthreads();
    #pragma unroll
    for (int k = 0; k < 4; ++k) {
        int bin = k * 1024 + tid;
        unsigned bs = baseB[bin];
        if (b == 0) binStartG[bin] = bs;    // publish for rank_kernel
        baseB[bin] = bs + pbh[(size_t)b * NBKT + bin];
        lofs[bin] = 0u;
    }
    __syncthreads();

    const float* cb = conf + (size_t)b * N_;
    #pragma unroll
    for (int s4 = 0; s4 < 4; ++s4) {
        int n = s4 * 1024 + tid;
        if (n < N_) {
            float c = cb[n];
            unsigned bin = bucket_of(c);
            unsigned lo = atomicAdd(&lofs[bin], 1u);   // LDS atomic
            unsigned idx = (unsigned)(b * N_ + n);
            sKey[baseB[bin] + lo] = ((u64)__float_as_uint(c) << 32) | (u64)(0xFFFFFFFFu - idx);
        }
    }
}

// ---- Rank: one WAVE per TP slot; lanes scan 2 keys each (16B loads) -------
__global__ __launch_bounds__(256) void rank_kernel(
    const float* __restrict__ conf,
    const int* __restrict__ tpIdx,
    const int* __restrict__ cnt,
    const unsigned* __restrict__ total,
    const unsigned* __restrict__ binStart,
    const u64* __restrict__ sKey,
    int* __restrict__ tpRank)
{
    const int lane = threadIdx.x & 63;
    const int w = (blockIdx.x << 2) | (threadIdx.x >> 6);   // global wave id
    if (w >= 2 * NL_) return;
    const int thr_i = w / NL_;
    const int t = w - thr_i * NL_;
    const int batch = t / G_;
    const int j = t - batch * G_;

    if (j < cnt[thr_i * B_ + batch]) {
        int e = tpIdx[thr_i * NL_ + t];
        float c = conf[e];
        u64 keyE = ((u64)__float_as_uint(c) << 32) | (u64)(0xFFFFFFFFu - (unsigned)e);
        unsigned bin = bucket_of(c);
        unsigned lo = binStart[bin], n = total[bin];
        unsigned hi = lo + n;
        int r = M_ - (int)hi;            // strictly-better buckets
        // 2 keys/lane via 16B aligned loads; range-masked (bit-exact preds).
        // 16B read may touch [lo&~1, lo+n+1) -- at most 8B past the bucket,
        // still inside sKey/ws; masked lanes contribute 0.
        for (unsigned base = lo & ~1u; base < hi; base += 128) {
            unsigned k = base + lane * 2;
            u64 v0 = 0ull, v1 = 0ull;
            if (k < hi) {                // aligned 16B load (k even)
                ulonglong2 vv = *(const ulonglong2*)(sKey + k);
                v0 = vv.x; v1 = vv.y;
            }
            bool p0 = (k >= lo) && (k < hi) && (v0 > keyE);
            bool p1 = (k + 1 >= lo) && (k + 1 < hi) && (v1 > keyE);
            r += (int)__popcll(__ballot(p0));
            r += (int)__popcll(__ballot(p1));
        }
        if (lane == 0) tpRank[thr_i * NL_ + t] = r;
    } else {
        if (lane == 0) tpRank[thr_i * NL_ + t] = M_ + t;   // distinct sentinel
    }
}

// ---- SortAP: counting sort of the 12800 DISTINCT TP ranks in LDS, then AP.
// One block per threshold. Own radix: rank>>9 -> SBKT=2048 buckets; valid
// ranks -> beta <= 1999; sentinels M_+t -> beta in [2000, 2025] < 2048.
__global__ __launch_bounds__(1024) void sortap_kernel(
    const int* __restrict__ tpRank,
    float* __restrict__ out)
{
    const int C = 13;   // 1024*13 = 13312 >= NL_
    union U1 { unsigned wtot[16]; float wmaxs[16]; };
    union U2 { unsigned hist[SBKT]; double red[1024]; };   // 8 KiB
    __shared__ int sr[NL_];            // 51.2 KiB: member list -> sorted ranks
    __shared__ U1 u1;
    __shared__ U2 u2;
    const int thr_i = blockIdx.x;
    const int t = threadIdx.x;
    const int lane = t & 63;
    const int wv = t >> 6;

    u2.hist[t] = 0u; u2.hist[t + 1024] = 0u;
    __syncthreads();

    // load ranks (coalesced), histogram by rank>>9
    int r[C]; unsigned beta[C];
    #pragma unroll
    for (int k = 0; k < C; ++k) {
        int i = t + k * 1024;
        if (i < NL_) {
            int rr = tpRank[thr_i * NL_ + i];
            r[k] = rr;
            unsigned bb = ((unsigned)rr) >> 9;
            beta[k] = bb > (SBKT - 1) ? (SBKT - 1) : bb;
            atomicAdd(&u2.hist[beta[k]], 1u);
        } else { r[k] = 0; beta[k] = 0xFFFFFFFFu; }
    }
    __syncthreads();

    // shuffle-based exclusive scan of hist (2048 bins, 2/thread)
    unsigned h0 = u2.hist[2 * t], h1 = u2.hist[2 * t + 1];
    unsigned own = h0 + h1;
    unsigned inc = own;
    #pragma unroll
    for (int off = 1; off < 64; off <<= 1) {
        unsigned o = __shfl_up(inc, off, 64);
        if (lane >= off) inc += o;
    }
    if (lane == 63) u1.wtot[wv] = inc;
    __syncthreads();
    if (wv == 0) {
        unsigned w = (lane < 16) ? u1.wtot[lane] : 0u;
        unsigned wi = w;
        #pragma unroll
        for (int off = 1; off < 16; off <<= 1) {
            unsigned o = __shfl_up(wi, off, 64);
            if (lane >= off) wi += o;
        }
        if (lane < 16) u1.wtot[lane] = wi - w;
    }
    __syncthreads();
    unsigned base = (inc - own) + u1.wtot[wv];   // exclusive prefix of own
    __syncthreads();                             // all u1 reads done
    u2.hist[2 * t] = base;                 // hist := exclusive bucket starts
    u2.hist[2 * t + 1] = base + h0;
    __syncthreads();

    // arrival scatter: hist becomes per-bucket cursor -> ends
    #pragma unroll
    for (int k = 0; k < C; ++k)
        if (beta[k] != 0xFFFFFFFFu) {
            unsigned slot = atomicAdd(&u2.hist[beta[k]], 1u);
            sr[slot] = r[k];
        }
    __syncthreads();
    // now hist[b] == end(b); start(b) == (b ? hist[b-1] : 0)

    // exact position = start + #{smaller in bucket}; ranks are distinct
    int p[C];
    #pragma unroll
    for (int k = 0; k < C; ++k) {
        if (beta[k] != 0xFFFFFFFFu) {
            unsigned st = (beta[k] == 0u) ? 0u : u2.hist[beta[k] - 1];
            unsigned en = u2.hist[beta[k]];
            int c = 0;
            for (unsigned j = st; j < en; ++j) c += (sr[j] < r[k]);
            p[k] = (int)st + c;
        } else p[k] = -1;
    }
    __syncthreads();                       // member reads done
    #pragma unroll
    for (int k = 0; k < C; ++k)            // bijection: every slot written
        if (p[k] >= 0) sr[p[k]] = r[k];
    __syncthreads();

    // ---- AP phase: identical math to R14's ap_kernel ----
    float pr[C]; int rk[C];
    #pragma unroll
    for (int k = 0; k < C; ++k) {
        int i = t * C + k;
        rk[k] = (i < NL_) ? sr[i] : 0x7FFFFFFF;
        pr[k] = (rk[k] < M_) ? (float)(i + 1) / (float)(rk[k] + 1) : -1.0f;
    }
    float suf[C];
    float run = -1.0f;
    #pragma unroll
    for (int k = C - 1; k >= 0; --k) { run = fmaxf(run, pr[k]); suf[k] = run; }

    // shuffle-based suffix max: follow(t) = max over threads > t of run
    float m = run;
    #pragma unroll
    for (int off = 1; off < 64; off <<= 1) {
        float o = __shfl_down(m, off, 64);
        if (lane + off < 64) m = fmaxf(m, o);
    }
    float f_in = __shfl_down(m, 1, 64);    // suffix from lane+1 in-wave
    if (lane == 63) f_in = -1.0f;
    if (lane == 0) u1.wmaxs[wv] = m;       // wave max
    __syncthreads();
    if (wv == 0) {
        float wm = (lane < 16) ? u1.wmaxs[lane] : -1.0f;
        float mi = wm;
        #pragma unroll
        for (int off = 1; off < 16; off <<= 1) {
            float o = __shfl_down(mi, off, 64);
            if (lane + off < 64) mi = fmaxf(mi, o);
        }
        float fw = __shfl_down(mi, 1, 64); // suffix from wave lane+1
        if (lane >= 15) fw = -1.0f;
        if (lane < 16) u1.wmaxs[lane] = fw;
    }
    __syncthreads();
    float follow = fmaxf(f_in, u1.wmaxs[wv]);

    double acc = 0.0;
    #pragma unroll
    for (int k = 0; k < C; ++k) {
        int i = t * C + k;
        if (rk[k] >= 1 && rk[k] < M_) {   // global rank 0 excluded by ref curve
            float smax = fmaxf(suf[k], follow);
            float rhi = (float)(i + 1) / 12800.0f;
            float rlo = (float)i / 12800.0f;
            acc += (double)((rhi - rlo) * smax);
        }
    }
    __syncthreads();                       // hist reads long done; red aliases it
    u2.red[t] = acc;
    __syncthreads();
    for (int off = 512; off >= 1; off >>= 1) {
        if (t < off) u2.red[t] += u2.red[t + off];
        __syncthreads();
    }
    if (t == 0) out[thr_i] = (float)u2.red[0];
}

extern "C" void kernel_launch(void* const* d_in, const int* in_sizes, int n_in,
                              void* d_out, int out_size, void* d_ws, size_t ws_size,
                              hipStream_t stream) {
    const float* scores = (const float*)d_in[0];   // [B,N]
    const float* seg    = (const float*)d_in[1];   // [B,N,2]
    const float* gts    = (const float*)d_in[2];   // [B,G,2]
    float* out = (float*)d_out;

    char* p = (char*)d_ws;
    int*            cnt        = (int*)p;             p += 4096;                  // 2KB used
    int*            tpIdx      = (int*)p;             p += 2 * NL_ * 4;           // 100 KB
    int*            tpRank     = (int*)p;             p += 2 * NL_ * 4;           // 100 KB
    unsigned*       total      = (unsigned*)p;        p += NBKT * 4;              // 16 KB
    unsigned*       binStart   = (unsigned*)p;        p += NBKT * 4;              // 16 KB
    unsigned short* pbh        = (unsigned short*)p;  p += (size_t)B_ * NBKT * 2; // 2 MB
    u64*            sKey       = (u64*)p;             p += (size_t)M_ * 8 + 16;   // 8 MB (+pad)
    (void)ws_size; (void)in_sizes; (void)n_in; (void)out_size;

    // No memset: every workspace word read downstream is written upstream.
    tp_kernel<<<B_, 1024, 0, stream>>>(seg, gts, scores, tpIdx, cnt, pbh);
    s1_kernel<<<NBKT / 32, 256, 0, stream>>>(pbh, total);
    scatter_kernel<<<B_, 1024, 0, stream>>>(scores, pbh, total, binStart, sKey);
    rank_kernel<<<(2 * NL_ + 3) / 4, 256, 0, stream>>>(scores, tpIdx, cnt,
                                                       total, binStart, sKey, tpRank);
    sortap_kernel<<<2, 1024, 0, stream>>>(tpRank, out);
}